// Round 4
// baseline (390.885 us; speedup 1.0000x reference)
//
#include <hip/hip_runtime.h>
#include <stdint.h>

#define TDIM 4096
#define CDIM 256
#define NMAT 8

typedef __attribute__((ext_vector_type(8))) __bf16 bf16x8;
typedef __attribute__((ext_vector_type(4))) float f32x4;

__device__ __forceinline__ unsigned short f2bf(float f) {
  unsigned int u = __float_as_uint(f);
  return (unsigned short)((u + 0x7FFFu + ((u >> 16) & 1u)) >> 16);
}
__device__ __forceinline__ void g2lds16(const void* g, void* l) {
  __builtin_amdgcn_global_load_lds((__attribute__((address_space(1))) void*)(void*)g,
                                   (__attribute__((address_space(3))) void*)l, 16, 0, 0);
}
__device__ __forceinline__ unsigned long long shfl_xor_u64(unsigned long long v, int m) {
  int lo = __shfl_xor((int)(unsigned int)(v & 0xFFFFFFFFull), m);
  int hi = __shfl_xor((int)(unsigned int)(v >> 32), m);
  return ((unsigned long long)(unsigned int)hi << 32) | (unsigned int)lo;
}

// ---------------- prep (8-matrix): fp32 -> bf16 + row sq-norms (fp32, exact) -------------
__global__ __launch_bounds__(256) void prep_kernel(
    const float* __restrict__ xb, const float* __restrict__ xa,
    unsigned short* __restrict__ xhi, float* __restrict__ sq) {
  const int wid = threadIdx.x >> 6, lane = threadIdx.x & 63;
  const int gr = blockIdx.x * 4 + wid;            // global row 0..32767 (mb*4096+row)
  const int mb = gr >> 12;
  const size_t rowoff = (size_t)gr * CDIM;
  const float* src = (mb < 4) ? (xb + rowoff) : (xa + rowoff - (size_t)4 * TDIM * CDIM);

  float4 v = ((const float4*)src)[lane];          // lane covers cols [4*lane, 4*lane+4)
  float vv[4] = {v.x, v.y, v.z, v.w};
  unsigned short h[4];
  float ss = 0.f;
#pragma unroll
  for (int c = 0; c < 4; ++c) {
    h[c] = f2bf(vv[c]);
    ss += vv[c] * vv[c];
  }
  *(ushort4*)&xhi[rowoff + lane * 4] = make_ushort4(h[0], h[1], h[2], h[3]);
#pragma unroll
  for (int off = 32; off; off >>= 1) ss += __shfl_down(ss, off);
  if (lane == 0) sq[gr] = ss;
}

// ---------------- prep (4-matrix / single-source variant for the small-ws path) ----------
__global__ __launch_bounds__(256) void prep4_kernel(
    const float* __restrict__ src0, unsigned short* __restrict__ xhi,
    float* __restrict__ sq4) {
  const int wid = threadIdx.x >> 6, lane = threadIdx.x & 63;
  const int gr = blockIdx.x * 4 + wid;            // local row 0..16383
  const size_t rowoff = (size_t)gr * CDIM;
  float4 v = ((const float4*)(src0 + rowoff))[lane];
  float vv[4] = {v.x, v.y, v.z, v.w};
  unsigned short h[4];
  float ss = 0.f;
#pragma unroll
  for (int c = 0; c < 4; ++c) {
    h[c] = f2bf(vv[c]);
    ss += vv[c] * vv[c];
  }
  *(ushort4*)&xhi[rowoff + lane * 4] = make_ushort4(h[0], h[1], h[2], h[3]);
#pragma unroll
  for (int off = 32; off; off >>= 1) ss += __shfl_down(ss, off);
  if (lane == 0) sq4[gr] = ss;
}

// ---------------- gram: 256x256-tile bf16 MFMA GEMM, K=256, BK=64, single-buffered -------
// 8 waves (2x4, wave tile 128x64), 64 KB LDS SINGLE-buffered -> 2 blocks/CU resident
// (the R1-proven implicit inter-block overlap), with 256^2's halved staged traffic
// (278 MB vs 540 MB at 128^2). Sync structure = R1's proven {sync; stage; drain+sync;
// compute} — no intra-block pipelining (R2/R3 showed it loses to inter-block overlap).
// Indexing/fragments/epilogue = R3's (harness-verified).
__global__ __launch_bounds__(512, 4) void gram_kernel(
    const unsigned short* __restrict__ xhi, const float* __restrict__ sq,
    unsigned long long* __restrict__ adj, int mb_base, int mbits) {
  __shared__ unsigned short As[256 * 64];   // [row][64 bf16], granule-swizzled
  __shared__ unsigned short Bs[256 * 64];

  const int tid = threadIdx.x;
  const int wid = tid >> 6, lane = tid & 63;
  const int wr = wid >> 2, wc = wid & 3;          // 2x4 waves, each 128x64 out

  // compact upper-tri grid: blockIdx = pair*(2^mbits) + mbl (matrix<->XCD pinning)
  const int mbl = blockIdx.x & ((1 << mbits) - 1);
  const int mb = mb_base + mbl;
  int rem = blockIdx.x >> mbits;                  // 0..135 (16x17/2 tiles of 256^2)
  int ti = 0;
  while (rem >= 16 - ti) { rem -= 16 - ti; ++ti; }
  const int tj = ti + rem;

  const unsigned short* hi = xhi + (size_t)mbl * TDIM * CDIM;  // xhi indexed by LOCAL mb
  const float* sqm = sq + (size_t)mb * TDIM;                   // sq indexed by GLOBAL mb

  f32x4 acc[8][4] = {};

  const int ldrow = (lane >> 3);                  // 0..7 within 8-row chunk
  const int ldcol = ((lane & 7) ^ ldrow) * 8;     // inverse-swizzled source granule col

  for (int ks = 0; ks < 4; ++ks) {                // K = 256 = 4 x 64
    const int kcol = ks * 64;
    __syncthreads();                               // prev compute done reading LDS
#pragma unroll
    for (int i = 0; i < 4; ++i) {
      const int chunk = wid * 4 + i;               // 32 chunks of 8 rows each (1KB)
      const int row = chunk * 8 + ldrow;
      g2lds16(hi + (size_t)(ti * 256 + row) * CDIM + kcol + ldcol, &As[chunk * 512]);
      g2lds16(hi + (size_t)(tj * 256 + row) * CDIM + kcol + ldcol, &Bs[chunk * 512]);
    }
    asm volatile("s_waitcnt vmcnt(0)" ::: "memory");  // staged data landed
    __syncthreads();
#pragma unroll
    for (int kk = 0; kk < 2; ++kk) {
      const int hi16 = lane >> 4;
      bf16x8 a[8], b[4];
#pragma unroll
      for (int m = 0; m < 8; ++m) {
        const int row = wr * 128 + m * 16 + (lane & 15);
        a[m] = *(const bf16x8*)&As[row * 64 + (((kk * 4 + hi16) ^ (row & 7)) * 8)];
      }
#pragma unroll
      for (int n = 0; n < 4; ++n) {
        const int row = wc * 64 + n * 16 + (lane & 15);
        b[n] = *(const bf16x8*)&Bs[row * 64 + (((kk * 4 + hi16) ^ (row & 7)) * 8)];
      }
#pragma unroll
      for (int m = 0; m < 8; ++m)
#pragma unroll
        for (int n = 0; n < 4; ++n)
          acc[m][n] = __builtin_amdgcn_mfma_f32_16x16x32_bf16(a[m], b[n], acc[m][n], 0, 0, 0);
    }
  }

  // norms (L2-hot; loaded post-loop)
  float4 srv[8];
#pragma unroll
  for (int m = 0; m < 8; ++m)
    srv[m] = *(const float4*)&sqm[ti * 256 + wr * 128 + m * 16 + (lane >> 4) * 4];
  float scv[4];
#pragma unroll
  for (int n = 0; n < 4; ++n) scv[n] = sqm[tj * 256 + wc * 64 + n * 16 + (lane & 15)];

  // epilogue: d2 = sq_i + sq_j - 2*G, two 64x64 halves per wave. Ballots are
  // wave-uniform; lane L self-assembles row L of the half at its (ml,r) iteration.
  const float EPS2 = (float)(22.6 * 22.6);
  unsigned long long* adjm = adj + (size_t)mb * TDIM * 64;   // 64 u64 words per row
  const int gt = (lane >> 2) & 3;
  const int mtgt = lane >> 4, rtgt = lane & 3;

#pragma unroll
  for (int h = 0; h < 2; ++h) {
    unsigned long long vrow = 0;
#pragma unroll
    for (int ml = 0; ml < 4; ++ml) {
      const int m = h * 4 + ml;
#pragma unroll
      for (int r = 0; r < 4; ++r) {
        const float srr = ((const float*)&srv[m])[r];
        unsigned long long bl[4];
#pragma unroll
        for (int n = 0; n < 4; ++n) {
          const float d2 = srr + scv[n] - 2.0f * acc[m][n][r];
          bl[n] = __ballot(d2 < EPS2);             // bit l <-> (row 4*(l>>4)+r, col n*16+(l&15))
        }
        if (ml == mtgt && r == rtgt)
          vrow = ((bl[0] >> (16 * gt)) & 0xFFFFULL)         | (((bl[1] >> (16 * gt)) & 0xFFFFULL) << 16) |
                 (((bl[2] >> (16 * gt)) & 0xFFFFULL) << 32) | (((bl[3] >> (16 * gt)) & 0xFFFFULL) << 48);
      }
    }
    // vrow = row `lane` of this wave's h-th 64x64 block: one coalesced store
    adjm[(size_t)(ti * 256 + wr * 128 + h * 64 + lane) * 64 + tj * 4 + wc] = vrow;

    // fused mirror: 64x64 bit transpose (butterfly) + store symmetric block
    if (ti != tj) {
      const unsigned long long mk[6] = {
          0x5555555555555555ull, 0x3333333333333333ull, 0x0F0F0F0F0F0F0F0Full,
          0x00FF00FF00FF00FFull, 0x0000FFFF0000FFFFull, 0x00000000FFFFFFFFull};
#pragma unroll
      for (int s = 0; s < 6; ++s) {
        const int d = 1 << s;
        const unsigned long long msk = mk[s];
        unsigned long long t = shfl_xor_u64(vrow, d);
        if ((lane & d) == 0) vrow = (vrow & msk) | ((t & msk) << d);
        else                 vrow = (vrow & ~msk) | ((t & ~msk) >> d);
      }
      adjm[(size_t)(tj * 256 + wc * 64 + lane) * 64 + ti * 4 + wr * 2 + h] = vrow;
    }
  }
}

// ---------------- cc pass 1: min set bit per row + per-block edge popcount (no atomics) --
__global__ __launch_bounds__(256) void cc_pass1_kernel(const unsigned long long* __restrict__ adj,
                                                       int* __restrict__ gnxt,
                                                       unsigned int* __restrict__ edgepart) {
  __shared__ unsigned int wcnt[4];
  const int wid = threadIdx.x >> 6, lane = threadIdx.x & 63;
  const int grow = blockIdx.x * 4 + wid;          // 0..32767 (1024 blocks per matrix)
  unsigned long long w = adj[(size_t)grow * 64 + lane];
  int cand = w ? (lane * 64 + __ffsll(w) - 1) : 0x7fffffff;
  unsigned int c = (unsigned int)__popcll(w);
#pragma unroll
  for (int off = 32; off; off >>= 1) {
    cand = min(cand, __shfl_down(cand, off));
    c += __shfl_down(c, off);
  }
  if (lane == 0) {
    gnxt[grow] = min(cand, grow & (TDIM - 1));    // diag bit => cand <= row
    wcnt[wid] = c;
  }
  __syncthreads();
  if (threadIdx.x == 0)
    edgepart[blockIdx.x] = wcnt[0] + wcnt[1] + wcnt[2] + wcnt[3];
}

// ---------------- cc iterate: pointer jump + min-label propagation (thread-per-row) ------
__global__ __launch_bounds__(1024) void cc_iter_kernel(const unsigned long long* __restrict__ adj,
                                                       const int* __restrict__ gnxt,
                                                       int* __restrict__ ncomp) {
  __shared__ int lab[TDIM];
  __shared__ int nxt[TDIM];
  __shared__ int changed;
  __shared__ int croots;
  const int mb = blockIdx.x;
  const unsigned long long* A = adj + (size_t)mb * TDIM * 64;
  const int tid = threadIdx.x;

  for (int i = tid; i < TDIM; i += 1024) nxt[i] = gnxt[mb * TDIM + i];
  __syncthreads();
  for (int i = tid; i < TDIM; i += 1024) lab[i] = nxt[nxt[i]];  // pointer jump
  __syncthreads();

  for (int it = 0; it < 96; ++it) {
    if (tid == 0) changed = 0;
    __syncthreads();
    for (int i = tid; i < TDIM; i += 1024) {      // one row per thread; label 0 = floor
      const int cur = lab[i];
      int mn = cur;
      if (cur > 0) {
        for (int wd = 0; wd < 64 && mn > 0; ++wd) {
          unsigned long long w = A[(size_t)i * 64 + wd];
          while (w && mn > 0) {
            const int bit = __ffsll(w) - 1;
            w &= w - 1;
            mn = min(mn, lab[wd * 64 + bit]);
          }
        }
        if (mn < cur) changed = 1;                // benign LDS race: all write 1
      }
      nxt[i] = mn;
    }
    __syncthreads();
    const int ch = changed;
    for (int i = tid; i < TDIM; i += 1024) lab[i] = nxt[nxt[i]];  // pointer jump
    __syncthreads();
    if (!ch) break;                               // stable => converged (symmetric adj)
  }

  if (tid == 0) croots = 0;
  __syncthreads();
  int c = 0;
  for (int i = tid; i < TDIM; i += 1024) c += (lab[i] == i);
  atomicAdd(&croots, c);
  __syncthreads();
  if (tid == 0) ncomp[mb] = croots;
}

// ---------------- finalize: sum edge partials; betti = max(0, E - T + C); mean(diff^2) ---
__global__ __launch_bounds__(512) void final_kernel(const unsigned int* __restrict__ edgepart,
                                                    const int* __restrict__ ncomp,
                                                    float* __restrict__ out) {
  __shared__ unsigned long long es[8];
  const int wid = threadIdx.x >> 6, lane = threadIdx.x & 63;  // wave wid sums matrix wid
  unsigned long long s = 0;
  for (int i = lane; i < 1024; i += 64) s += edgepart[wid * 1024 + i];
#pragma unroll
  for (int off = 32; off; off >>= 1) s += __shfl_down(s, off);
  if (lane == 0) es[wid] = s;
  __syncthreads();
  if (threadIdx.x == 0) {
    double acc = 0.0;
    for (int b = 0; b < 4; ++b) {
      long long e0 = (long long)(es[b] >> 1);               // sum(adj)//2, diag included
      long long bet0 = e0 - TDIM + (long long)ncomp[b];
      if (bet0 < 0) bet0 = 0;
      long long e1 = (long long)(es[4 + b] >> 1);
      long long bet1 = e1 - TDIM + (long long)ncomp[4 + b];
      if (bet1 < 0) bet1 = 0;
      double d = (double)(bet1 - bet0);
      acc += d * d;
    }
    out[0] = (float)(acc * 0.25);
  }
}

extern "C" void kernel_launch(void* const* d_in, const int* in_sizes, int n_in,
                              void* d_out, int out_size, void* d_ws, size_t ws_size,
                              hipStream_t stream) {
  (void)in_sizes; (void)n_in; (void)out_size;
  const float* xb = (const float*)d_in[0];
  const float* xa = (const float*)d_in[1];
  char* ws = (char*)d_ws;

  // Footprint guard: the 1-shot layout needs 33.85 MB. If the harness workspace is
  // smaller, fall back to a 25.5 MB split pipeline (4-matrix xhi reused across two
  // prep+gram rounds).
  const bool big = (ws_size == 0) || (ws_size >= ((size_t)34 << 20));

  if (big) {
    const size_t XHI_OFF = 0;                                   // 16 MB
    const size_t ADJ_OFF = (size_t)NMAT * TDIM * CDIM * 2;      // 16 MB (8 * 4096 * 64 u64)
    const size_t SQ_OFF  = ADJ_OFF + (size_t)NMAT * TDIM * 64 * 8;
    const size_t NC_OFF  = SQ_OFF + (size_t)NMAT * TDIM * 4;    // ncomp[8]
    const size_t GNXT_OFF = NC_OFF + 64;                        // 128 KB
    const size_t EDGE_OFF = GNXT_OFF + (size_t)NMAT * TDIM * 4; // 32 KB

    unsigned short* xhi = (unsigned short*)(ws + XHI_OFF);
    unsigned long long* adj = (unsigned long long*)(ws + ADJ_OFF);
    float* sq = (float*)(ws + SQ_OFF);
    int* ncomp = (int*)(ws + NC_OFF);
    int* gnxt = (int*)(ws + GNXT_OFF);
    unsigned int* edgepart = (unsigned int*)(ws + EDGE_OFF);

    prep_kernel<<<NMAT * TDIM / 4, 256, 0, stream>>>(xb, xa, xhi, sq);
    gram_kernel<<<NMAT * 136, 512, 0, stream>>>(xhi, sq, adj, 0, 3);
    cc_pass1_kernel<<<NMAT * TDIM / 4, 256, 0, stream>>>(adj, gnxt, edgepart);
    cc_iter_kernel<<<NMAT, 1024, 0, stream>>>(adj, gnxt, ncomp);
    final_kernel<<<1, 512, 0, stream>>>(edgepart, ncomp, (float*)d_out);
  } else {
    const size_t XHI_OFF = 0;                                   // 8 MB (4 matrices)
    const size_t ADJ_OFF = (size_t)4 * TDIM * CDIM * 2;         // 8,388,608
    const size_t SQ_OFF  = ADJ_OFF + (size_t)NMAT * TDIM * 64 * 8;  // 25,165,824
    const size_t NC_OFF  = SQ_OFF + (size_t)NMAT * TDIM * 4;
    const size_t GNXT_OFF = NC_OFF + 64;
    const size_t EDGE_OFF = GNXT_OFF + (size_t)NMAT * TDIM * 4; // ends ~25.46 MB

    unsigned short* xhi = (unsigned short*)(ws + XHI_OFF);
    unsigned long long* adj = (unsigned long long*)(ws + ADJ_OFF);
    float* sq = (float*)(ws + SQ_OFF);
    int* ncomp = (int*)(ws + NC_OFF);
    int* gnxt = (int*)(ws + GNXT_OFF);
    unsigned int* edgepart = (unsigned int*)(ws + EDGE_OFF);

    prep4_kernel<<<TDIM, 256, 0, stream>>>(xb, xhi, sq);                  // matrices 0..3
    gram_kernel<<<4 * 136, 512, 0, stream>>>(xhi, sq, adj, 0, 2);
    prep4_kernel<<<TDIM, 256, 0, stream>>>(xa, xhi, sq + (size_t)4 * TDIM);  // matrices 4..7
    gram_kernel<<<4 * 136, 512, 0, stream>>>(xhi, sq, adj, 4, 2);
    cc_pass1_kernel<<<NMAT * TDIM / 4, 256, 0, stream>>>(adj, gnxt, edgepart);
    cc_iter_kernel<<<NMAT, 1024, 0, stream>>>(adj, gnxt, ncomp);
    final_kernel<<<1, 512, 0, stream>>>(edgepart, ncomp, (float*)d_out);
  }
}

// Round 5
// 85.124 us; speedup vs baseline: 4.5920x; 4.5920x over previous
//
#include <hip/hip_runtime.h>
#include <stdint.h>

#define TDIM 4096
#define CDIM 256
#define NMAT 8

typedef __attribute__((ext_vector_type(8))) __bf16 bf16x8;
typedef __attribute__((ext_vector_type(4))) float f32x4;

__device__ __forceinline__ unsigned short f2bf(float f) {
  unsigned int u = __float_as_uint(f);
  return (unsigned short)((u + 0x7FFFu + ((u >> 16) & 1u)) >> 16);
}
__device__ __forceinline__ void g2lds16(const void* g, void* l) {
  __builtin_amdgcn_global_load_lds((__attribute__((address_space(1))) void*)(void*)g,
                                   (__attribute__((address_space(3))) void*)l, 16, 0, 0);
}
__device__ __forceinline__ unsigned long long shfl_xor_u64(unsigned long long v, int m) {
  int lo = __shfl_xor((int)(unsigned int)(v & 0xFFFFFFFFull), m);
  int hi = __shfl_xor((int)(unsigned int)(v >> 32), m);
  return ((unsigned long long)(unsigned int)hi << 32) | (unsigned int)lo;
}

// ---------------- prep (8-matrix): fp32 -> bf16 + row sq-norms (fp32, exact) -------------
__global__ __launch_bounds__(256) void prep_kernel(
    const float* __restrict__ xb, const float* __restrict__ xa,
    unsigned short* __restrict__ xhi, float* __restrict__ sq) {
  const int wid = threadIdx.x >> 6, lane = threadIdx.x & 63;
  const int gr = blockIdx.x * 4 + wid;            // global row 0..32767 (mb*4096+row)
  const int mb = gr >> 12;
  const size_t rowoff = (size_t)gr * CDIM;
  const float* src = (mb < 4) ? (xb + rowoff) : (xa + rowoff - (size_t)4 * TDIM * CDIM);

  float4 v = ((const float4*)src)[lane];          // lane covers cols [4*lane, 4*lane+4)
  float vv[4] = {v.x, v.y, v.z, v.w};
  unsigned short h[4];
  float ss = 0.f;
#pragma unroll
  for (int c = 0; c < 4; ++c) {
    h[c] = f2bf(vv[c]);
    ss += vv[c] * vv[c];
  }
  *(ushort4*)&xhi[rowoff + lane * 4] = make_ushort4(h[0], h[1], h[2], h[3]);
#pragma unroll
  for (int off = 32; off; off >>= 1) ss += __shfl_down(ss, off);
  if (lane == 0) sq[gr] = ss;
}

// ---------------- prep (4-matrix / single-source variant for the small-ws path) ----------
__global__ __launch_bounds__(256) void prep4_kernel(
    const float* __restrict__ src0, unsigned short* __restrict__ xhi,
    float* __restrict__ sq4) {
  const int wid = threadIdx.x >> 6, lane = threadIdx.x & 63;
  const int gr = blockIdx.x * 4 + wid;            // local row 0..16383
  const size_t rowoff = (size_t)gr * CDIM;
  float4 v = ((const float4*)(src0 + rowoff))[lane];
  float vv[4] = {v.x, v.y, v.z, v.w};
  unsigned short h[4];
  float ss = 0.f;
#pragma unroll
  for (int c = 0; c < 4; ++c) {
    h[c] = f2bf(vv[c]);
    ss += vv[c] * vv[c];
  }
  *(ushort4*)&xhi[rowoff + lane * 4] = make_ushort4(h[0], h[1], h[2], h[3]);
#pragma unroll
  for (int off = 32; off; off >>= 1) ss += __shfl_down(ss, off);
  if (lane == 0) sq4[gr] = ss;
}

// ---------------- gram: 128x128-tile bf16 MFMA GEMM, K=256 (R1-proven, 49.9 us) ----------
// 4 waves (2x2, wave tile 64x64), 32 KB LDS single-buffered, granule swizzle, no atomics,
// upper-triangle tiles only (528/matrix), mirror fused.
// R5 change vs R1: __launch_bounds__(256, 3) — cap regs at 170/wave so 3 blocks/CU can
// be resident (R1 measured 24.9% occupancy = 2 blocks; LDS allows 5; the limiter is a
// few regs over the 170 threshold). More resident blocks = more inter-block overlap of
// the per-K-step stage/drain stalls (the proven hiding mechanism; R2-R4 alternatives all
// regressed). NO other change to the proven structure.
__global__ __launch_bounds__(256, 3) void gram_kernel(
    const unsigned short* __restrict__ xhi, const float* __restrict__ sq,
    unsigned long long* __restrict__ adj, int mb_base, int mbits) {
  __shared__ unsigned short As[128 * 64];   // [row][64 bf16], granule-swizzled: g ^= row&7
  __shared__ unsigned short Bs[128 * 64];

  const int tid = threadIdx.x;
  const int wid = tid >> 6, lane = tid & 63;
  const int wr = wid >> 1, wc = wid & 1;          // 2x2 waves, each 64x64 out

  // compact upper-tri grid: blockIdx = pair*(2^mbits) + mbl (matrix<->XCD pinning)
  const int mbl = blockIdx.x & ((1 << mbits) - 1);
  const int mb = mb_base + mbl;
  int rem = blockIdx.x >> mbits;                  // 0..527
  int ti = 0;
  while (rem >= 32 - ti) { rem -= 32 - ti; ++ti; }
  const int tj = ti + rem;

  const unsigned short* hi = xhi + (size_t)mbl * TDIM * CDIM;  // xhi indexed by LOCAL mb
  const float* sqm = sq + (size_t)mb * TDIM;                   // sq indexed by GLOBAL mb

  f32x4 acc[4][4] = {};

  const int ldrow = (lane >> 3);                  // 0..7 within 8-row chunk
  const int ldcol = ((lane & 7) ^ ldrow) * 8;     // inverse-swizzled source granule col

  for (int ks = 0; ks < 4; ++ks) {                // K = 256 = 4 x 64
    const int kcol = ks * 64;
    __syncthreads();                               // prev compute done reading LDS
#pragma unroll
    for (int i = 0; i < 4; ++i) {
      const int chunk = wid * 4 + i;               // 16 chunks of 1KB per tile
      const int row = chunk * 8 + ldrow;
      g2lds16(hi + (size_t)(ti * 128 + row) * CDIM + kcol + ldcol, &As[chunk * 512]);
      g2lds16(hi + (size_t)(tj * 128 + row) * CDIM + kcol + ldcol, &Bs[chunk * 512]);
    }
    asm volatile("s_waitcnt vmcnt(0)" ::: "memory");  // staged data landed
    __syncthreads();
#pragma unroll
    for (int kk = 0; kk < 2; ++kk) {
      bf16x8 a[4], b[4];
      const int hi16 = lane >> 4;
#pragma unroll
      for (int m = 0; m < 4; ++m) {
        const int row = wr * 64 + m * 16 + (lane & 15);
        a[m] = *(const bf16x8*)&As[row * 64 + (((kk * 4 + hi16) ^ (row & 7)) * 8)];
      }
#pragma unroll
      for (int n = 0; n < 4; ++n) {
        const int row = wc * 64 + n * 16 + (lane & 15);
        b[n] = *(const bf16x8*)&Bs[row * 64 + (((kk * 4 + hi16) ^ (row & 7)) * 8)];
      }
#pragma unroll
      for (int m = 0; m < 4; ++m)
#pragma unroll
        for (int n = 0; n < 4; ++n)
          acc[m][n] = __builtin_amdgcn_mfma_f32_16x16x32_bf16(a[m], b[n], acc[m][n], 0, 0, 0);
    }
  }

  // epilogue: d2 = sq_i + sq_j - 2*G. Ballots are wave-uniform; lane L captures the
  // assembly for row L (= mtgt*16 + 4*gt + rtgt) at its designated (m,r) iteration.
  const float EPS2 = (float)(22.6 * 22.6);
  unsigned long long* adjm = adj + (size_t)mb * TDIM * 64;   // 64 u64 words per row
  const int gt = (lane >> 2) & 3;
  const int mtgt = lane >> 4, rtgt = lane & 3;
  unsigned long long vrow = 0;

  float4 srv[4];                                  // broadcast loads, L2-hot (16 KB/matrix)
#pragma unroll
  for (int m = 0; m < 4; ++m)
    srv[m] = *(const float4*)&sqm[ti * 128 + wr * 64 + m * 16 + (lane >> 4) * 4];
  float scv[4];
#pragma unroll
  for (int n = 0; n < 4; ++n) scv[n] = sqm[tj * 128 + wc * 64 + n * 16 + (lane & 15)];

#pragma unroll
  for (int m = 0; m < 4; ++m) {
#pragma unroll
    for (int r = 0; r < 4; ++r) {
      const float srr = ((const float*)&srv[m])[r];
      unsigned long long bl[4];
#pragma unroll
      for (int n = 0; n < 4; ++n) {
        const float d2 = srr + scv[n] - 2.0f * acc[m][n][r];
        bl[n] = __ballot(d2 < EPS2);               // bit l <-> (row 4*(l>>4)+r, col n*16+(l&15))
      }
      if (m == mtgt && r == rtgt)
        vrow = ((bl[0] >> (16 * gt)) & 0xFFFFULL)         | (((bl[1] >> (16 * gt)) & 0xFFFFULL) << 16) |
               (((bl[2] >> (16 * gt)) & 0xFFFFULL) << 32) | (((bl[3] >> (16 * gt)) & 0xFFFFULL) << 48);
    }
  }
  // vrow = row `lane` of this wave's 64x64 block: one store for the upper block
  adjm[(size_t)(ti * 128 + wr * 64 + lane) * 64 + tj * 2 + wc] = vrow;

  // fused mirror: 64x64 bit transpose (butterfly) + store symmetric block
  if (ti != tj) {
    const unsigned long long mk[6] = {
        0x5555555555555555ull, 0x3333333333333333ull, 0x0F0F0F0F0F0F0F0Full,
        0x00FF00FF00FF00FFull, 0x0000FFFF0000FFFFull, 0x00000000FFFFFFFFull};
#pragma unroll
    for (int s = 0; s < 6; ++s) {
      const int d = 1 << s;
      const unsigned long long m = mk[s];
      unsigned long long t = shfl_xor_u64(vrow, d);
      if ((lane & d) == 0) vrow = (vrow & m) | ((t & m) << d);
      else                 vrow = (vrow & ~m) | ((t & ~m) >> d);
    }
    adjm[(size_t)(tj * 128 + wc * 64 + lane) * 64 + ti * 2 + wr] = vrow;
  }
}

// ---------------- cc pass 1: min set bit per row + per-block edge popcount (no atomics) --
__global__ __launch_bounds__(256) void cc_pass1_kernel(const unsigned long long* __restrict__ adj,
                                                       int* __restrict__ gnxt,
                                                       unsigned int* __restrict__ edgepart) {
  __shared__ unsigned int wcnt[4];
  const int wid = threadIdx.x >> 6, lane = threadIdx.x & 63;
  const int grow = blockIdx.x * 4 + wid;          // 0..32767 (1024 blocks per matrix)
  unsigned long long w = adj[(size_t)grow * 64 + lane];
  int cand = w ? (lane * 64 + __ffsll(w) - 1) : 0x7fffffff;
  unsigned int c = (unsigned int)__popcll(w);
#pragma unroll
  for (int off = 32; off; off >>= 1) {
    cand = min(cand, __shfl_down(cand, off));
    c += __shfl_down(c, off);
  }
  if (lane == 0) {
    gnxt[grow] = min(cand, grow & (TDIM - 1));    // diag bit => cand <= row
    wcnt[wid] = c;
  }
  __syncthreads();
  if (threadIdx.x == 0)
    edgepart[blockIdx.x] = wcnt[0] + wcnt[1] + wcnt[2] + wcnt[3];
}

// ---------------- cc iterate: pointer jump + min-label propagation (thread-per-row) ------
__global__ __launch_bounds__(1024) void cc_iter_kernel(const unsigned long long* __restrict__ adj,
                                                       const int* __restrict__ gnxt,
                                                       int* __restrict__ ncomp) {
  __shared__ int lab[TDIM];
  __shared__ int nxt[TDIM];
  __shared__ int changed;
  __shared__ int croots;
  const int mb = blockIdx.x;
  const unsigned long long* A = adj + (size_t)mb * TDIM * 64;
  const int tid = threadIdx.x;

  for (int i = tid; i < TDIM; i += 1024) nxt[i] = gnxt[mb * TDIM + i];
  __syncthreads();
  for (int i = tid; i < TDIM; i += 1024) lab[i] = nxt[nxt[i]];  // pointer jump
  __syncthreads();

  for (int it = 0; it < 96; ++it) {
    if (tid == 0) changed = 0;
    __syncthreads();
    for (int i = tid; i < TDIM; i += 1024) {      // one row per thread; label 0 = floor
      const int cur = lab[i];
      int mn = cur;
      if (cur > 0) {
        for (int wd = 0; wd < 64 && mn > 0; ++wd) {
          unsigned long long w = A[(size_t)i * 64 + wd];
          while (w && mn > 0) {
            const int bit = __ffsll(w) - 1;
            w &= w - 1;
            mn = min(mn, lab[wd * 64 + bit]);
          }
        }
        if (mn < cur) changed = 1;                // benign LDS race: all write 1
      }
      nxt[i] = mn;
    }
    __syncthreads();
    const int ch = changed;
    for (int i = tid; i < TDIM; i += 1024) lab[i] = nxt[nxt[i]];  // pointer jump
    __syncthreads();
    if (!ch) break;                               // stable => converged (symmetric adj)
  }

  if (tid == 0) croots = 0;
  __syncthreads();
  int c = 0;
  for (int i = tid; i < TDIM; i += 1024) c += (lab[i] == i);
  atomicAdd(&croots, c);
  __syncthreads();
  if (tid == 0) ncomp[mb] = croots;
}

// ---------------- finalize: sum edge partials; betti = max(0, E - T + C); mean(diff^2) ---
__global__ __launch_bounds__(512) void final_kernel(const unsigned int* __restrict__ edgepart,
                                                    const int* __restrict__ ncomp,
                                                    float* __restrict__ out) {
  __shared__ unsigned long long es[8];
  const int wid = threadIdx.x >> 6, lane = threadIdx.x & 63;  // wave wid sums matrix wid
  unsigned long long s = 0;
  for (int i = lane; i < 1024; i += 64) s += edgepart[wid * 1024 + i];
#pragma unroll
  for (int off = 32; off; off >>= 1) s += __shfl_down(s, off);
  if (lane == 0) es[wid] = s;
  __syncthreads();
  if (threadIdx.x == 0) {
    double acc = 0.0;
    for (int b = 0; b < 4; ++b) {
      long long e0 = (long long)(es[b] >> 1);               // sum(adj)//2, diag included
      long long bet0 = e0 - TDIM + (long long)ncomp[b];
      if (bet0 < 0) bet0 = 0;
      long long e1 = (long long)(es[4 + b] >> 1);
      long long bet1 = e1 - TDIM + (long long)ncomp[4 + b];
      if (bet1 < 0) bet1 = 0;
      double d = (double)(bet1 - bet0);
      acc += d * d;
    }
    out[0] = (float)(acc * 0.25);
  }
}

extern "C" void kernel_launch(void* const* d_in, const int* in_sizes, int n_in,
                              void* d_out, int out_size, void* d_ws, size_t ws_size,
                              hipStream_t stream) {
  (void)in_sizes; (void)n_in; (void)out_size;
  const float* xb = (const float*)d_in[0];
  const float* xa = (const float*)d_in[1];
  char* ws = (char*)d_ws;

  // Footprint guard: the 1-shot layout needs 33.85 MB. If the harness workspace is
  // smaller, fall back to a 25.5 MB split pipeline (4-matrix xhi reused across two
  // prep+gram rounds).
  const bool big = (ws_size == 0) || (ws_size >= ((size_t)34 << 20));

  if (big) {
    const size_t XHI_OFF = 0;                                   // 16 MB
    const size_t ADJ_OFF = (size_t)NMAT * TDIM * CDIM * 2;      // 16 MB (8 * 4096 * 64 u64)
    const size_t SQ_OFF  = ADJ_OFF + (size_t)NMAT * TDIM * 64 * 8;
    const size_t NC_OFF  = SQ_OFF + (size_t)NMAT * TDIM * 4;    // ncomp[8]
    const size_t GNXT_OFF = NC_OFF + 64;                        // 128 KB
    const size_t EDGE_OFF = GNXT_OFF + (size_t)NMAT * TDIM * 4; // 32 KB

    unsigned short* xhi = (unsigned short*)(ws + XHI_OFF);
    unsigned long long* adj = (unsigned long long*)(ws + ADJ_OFF);
    float* sq = (float*)(ws + SQ_OFF);
    int* ncomp = (int*)(ws + NC_OFF);
    int* gnxt = (int*)(ws + GNXT_OFF);
    unsigned int* edgepart = (unsigned int*)(ws + EDGE_OFF);

    prep_kernel<<<NMAT * TDIM / 4, 256, 0, stream>>>(xb, xa, xhi, sq);
    gram_kernel<<<NMAT * 528, 256, 0, stream>>>(xhi, sq, adj, 0, 3);
    cc_pass1_kernel<<<NMAT * TDIM / 4, 256, 0, stream>>>(adj, gnxt, edgepart);
    cc_iter_kernel<<<NMAT, 1024, 0, stream>>>(adj, gnxt, ncomp);
    final_kernel<<<1, 512, 0, stream>>>(edgepart, ncomp, (float*)d_out);
  } else {
    const size_t XHI_OFF = 0;                                   // 8 MB (4 matrices)
    const size_t ADJ_OFF = (size_t)4 * TDIM * CDIM * 2;         // 8,388,608
    const size_t SQ_OFF  = ADJ_OFF + (size_t)NMAT * TDIM * 64 * 8;  // 25,165,824
    const size_t NC_OFF  = SQ_OFF + (size_t)NMAT * TDIM * 4;
    const size_t GNXT_OFF = NC_OFF + 64;
    const size_t EDGE_OFF = GNXT_OFF + (size_t)NMAT * TDIM * 4; // ends ~25.46 MB

    unsigned short* xhi = (unsigned short*)(ws + XHI_OFF);
    unsigned long long* adj = (unsigned long long*)(ws + ADJ_OFF);
    float* sq = (float*)(ws + SQ_OFF);
    int* ncomp = (int*)(ws + NC_OFF);
    int* gnxt = (int*)(ws + GNXT_OFF);
    unsigned int* edgepart = (unsigned int*)(ws + EDGE_OFF);

    prep4_kernel<<<TDIM, 256, 0, stream>>>(xb, xhi, sq);                  // matrices 0..3
    gram_kernel<<<4 * 528, 256, 0, stream>>>(xhi, sq, adj, 0, 2);
    prep4_kernel<<<TDIM, 256, 0, stream>>>(xa, xhi, sq + (size_t)4 * TDIM);  // matrices 4..7
    gram_kernel<<<4 * 528, 256, 0, stream>>>(xhi, sq, adj, 4, 2);
    cc_pass1_kernel<<<NMAT * TDIM / 4, 256, 0, stream>>>(adj, gnxt, edgepart);
    cc_iter_kernel<<<NMAT, 1024, 0, stream>>>(adj, gnxt, ncomp);
    final_kernel<<<1, 512, 0, stream>>>(edgepart, ncomp, (float*)d_out);
  }
}